// Round 9
// baseline (957.686 us; speedup 1.0000x reference)
//
#include <hip/hip_runtime.h>
#include <hip/hip_cooperative_groups.h>
namespace cg = cooperative_groups;

typedef unsigned short ushort_t;
typedef __attribute__((ext_vector_type(8))) short short8;
typedef __attribute__((ext_vector_type(4))) float floatx4;

#define BSZ   512
#define UNITS 256
#define IMG   64
#define STEPS 10
#define GATES 1024
// folded ext layout per batch row: [x_hat 4096 | h_dec 256 | h_enc 256]
#define KENC  4608
#define ESPLIT 8
#define DSPLIT 8

__device__ inline float b2f(ushort_t u) {
  union { float f; unsigned int i; } v; v.i = ((unsigned int)u) << 16; return v.f;
}
__device__ inline ushort_t f2b(float f) {
  unsigned int u = __float_as_uint(f);
  u += 0x7fffu + ((u >> 16) & 1u);          // round-to-nearest-even
  return (ushort_t)(u >> 16);
}
__device__ inline float sigm(float x) { return 1.f / (1.f + __expf(-x)); }

#define GLL(g, l) __builtin_amdgcn_global_load_lds(                      \
    (const __attribute__((address_space(1))) void*)(g),                  \
    (__attribute__((address_space(3))) void*)(l), 16, 0, 0)

// ---------------------------------------------------------------------------
// Weight prep kernels (once per launch)
// ---------------------------------------------------------------------------
__global__ __launch_bounds__(256) void k_prep_pix(const float* __restrict__ ek,
                                                  ushort_t* __restrict__ ohi,
                                                  ushort_t* __restrict__ olo) {
  __shared__ float T[64][68];
  int t = threadIdx.x;
  int pix0 = blockIdx.x * 64, n0 = blockIdx.y * 64;
  int r = t >> 2, seg = t & 3;
  int pix = pix0 + r;
  int ri = pix >> 6, ci = pix & 63;
  float4 acc4[4];
#pragma unroll
  for (int j = 0; j < 4; ++j) acc4[j] = float4{0.f, 0.f, 0.f, 0.f};
#pragma unroll
  for (int di = 0; di < 3; ++di) {
    int ii = ri - di;
    if (ii < 0 || (ii & 1)) continue;
    int oi = ii >> 1;  if (oi >= 32) continue;
#pragma unroll
    for (int dj = 0; dj < 3; ++dj) {
      int jj = ci - dj;
      if (jj < 0 || (jj & 1)) continue;
      int oj = jj >> 1;  if (oj >= 32) continue;
      const float* row = ek + (size_t)((oi * 32 + oj) * 9 + di * 3 + dj) * GATES
                         + n0 + seg * 16;
#pragma unroll
      for (int j = 0; j < 4; ++j) {
        float4 v = *(const float4*)(row + j * 4);
        acc4[j].x += v.x; acc4[j].y += v.y; acc4[j].z += v.z; acc4[j].w += v.w;
      }
    }
  }
#pragma unroll
  for (int j = 0; j < 4; ++j) *(float4*)&T[r][seg * 16 + j * 4] = acc4[j];
  __syncthreads();
  ushort_t thi[16], tlo[16];
#pragma unroll
  for (int j = 0; j < 16; ++j) {
    float v = T[seg * 16 + j][r];
    ushort_t h = f2b(v);
    thi[j] = h;
    tlo[j] = f2b(v - b2f(h));
  }
  size_t off = (size_t)(n0 + r) * KENC + pix0 + seg * 16;
  *(uint4*)(ohi + off)     = *(const uint4*)&thi[0];
  *(uint4*)(ohi + off + 8) = *(const uint4*)&thi[8];
  *(uint4*)(olo + off)     = *(const uint4*)&tlo[0];
  *(uint4*)(olo + off + 8) = *(const uint4*)&tlo[8];
}

__global__ __launch_bounds__(256) void k_prep_sum(const float* __restrict__ s0,
                                                  const float* __restrict__ s1,
                                                  int src_ld, int out_ld, int koff,
                                                  ushort_t* __restrict__ ohi,
                                                  ushort_t* __restrict__ olo) {
  __shared__ float T[64][68];
  int t = threadIdx.x;
  int k0 = blockIdx.x * 64, n0 = blockIdx.y * 64;
  int r = t >> 2, seg = t & 3;
  const float* src = s0 + (size_t)(k0 + r) * src_ld + n0 + seg * 16;
  const float* src2 = s1 ? (s1 + (size_t)(k0 + r) * src_ld + n0 + seg * 16) : nullptr;
#pragma unroll
  for (int j = 0; j < 4; ++j) {
    float4 v = *(const float4*)(src + j * 4);
    if (src2) {
      float4 w = *(const float4*)(src2 + j * 4);
      v.x += w.x; v.y += w.y; v.z += w.z; v.w += w.w;
    }
    *(float4*)&T[r][seg * 16 + j * 4] = v;
  }
  __syncthreads();
  ushort_t thi[16], tlo[16];
#pragma unroll
  for (int j = 0; j < 16; ++j) {
    float v = T[seg * 16 + j][r];
    ushort_t h = f2b(v);
    thi[j] = h;
    tlo[j] = f2b(v - b2f(h));
  }
  size_t off = (size_t)(n0 + r) * out_ld + koff + k0 + seg * 16;
  *(uint4*)(ohi + off)     = *(const uint4*)&thi[0];
  *(uint4*)(ohi + off + 8) = *(const uint4*)&thi[8];
  *(uint4*)(olo + off)     = *(const uint4*)&tlo[0];
  *(uint4*)(olo + off + 8) = *(const uint4*)&tlo[8];
}

__global__ __launch_bounds__(256) void k_xhat0(const float* __restrict__ x,
                                               ushort_t* __restrict__ ehi,
                                               ushort_t* __restrict__ elo) {
  int tid = blockIdx.x * 256 + threadIdx.x;       // 512*4096
  int b = tid >> 12, pix = tid & 4095;
  float v = x[tid] - 0.5f;
  ushort_t h = f2b(v);
  ehi[(size_t)b * KENC + pix] = h;
  elo[(size_t)b * KENC + pix] = f2b(v - b2f(h));
}

__global__ __launch_bounds__(256) void k_init(ushort_t* __restrict__ ehi,
                                              ushort_t* __restrict__ elo,
                                              ushort_t* __restrict__ dhi,
                                              ushort_t* __restrict__ dlo) {
  int b = blockIdx.x, u = threadIdx.x;
  ehi[(size_t)b * KENC + 4096 + u] = 0; ehi[(size_t)b * KENC + 4352 + u] = 0;
  elo[(size_t)b * KENC + 4096 + u] = 0; elo[(size_t)b * KENC + 4352 + u] = 0;
  dhi[(size_t)b * 512 + u] = 0; dhi[(size_t)b * 512 + 256 + u] = 0;
  dlo[(size_t)b * 512 + u] = 0; dlo[(size_t)b * 512 + 256 + u] = 0;
}

// ===========================================================================
// FALLBACK PATH (R8 kernels) — used only if cooperative occupancy < 2/CU
// ===========================================================================
#define TM 128
#define TN 128
#define BK 32

__global__ __launch_bounds__(512, 2) void gemm128(
    const ushort_t* __restrict__ Ahi, const ushort_t* __restrict__ Alo, int lda,
    const ushort_t* __restrict__ Bhi, const ushort_t* __restrict__ Blo, int ldbt,
    float* __restrict__ C, int ldc, int kiters) {
  __shared__ ushort_t ls[2][4][TM * BK];
  int t = threadIdx.x;
  int m0 = blockIdx.y * TM, n0 = blockIdx.x * TN;
  int z = blockIdx.z;
  int kstart = z * kiters * BK;
  int lane = t & 63, w = t >> 6;
  int wm = w >> 1, wn = w & 1;
  int q = lane >> 4, c16 = lane & 15;

  const ushort_t* pAh = Ahi + (size_t)(m0 + (t >> 2)) * lda + kstart + (t & 3) * 8;
  const ushort_t* pAl = Alo + (size_t)(m0 + (t >> 2)) * lda + kstart + (t & 3) * 8;
  const ushort_t* pBh = Bhi + (size_t)(n0 + (t >> 2)) * ldbt + kstart + (t & 3) * 8;
  const ushort_t* pBl = Blo + (size_t)(n0 + (t >> 2)) * ldbt + kstart + (t & 3) * 8;
  const int d0 = t * 8;

  floatx4 acc[2][4];
#pragma unroll
  for (int i = 0; i < 2; ++i)
#pragma unroll
    for (int j = 0; j < 4; ++j) acc[i][j] = floatx4{0.f, 0.f, 0.f, 0.f};

  GLL(pAh, &ls[0][0][d0]); GLL(pAl, &ls[0][1][d0]);
  GLL(pBh, &ls[0][2][d0]); GLL(pBl, &ls[0][3][d0]);
  pAh += BK; pAl += BK; pBh += BK; pBl += BK;
  __syncthreads();

  for (int kt = 0; kt < kiters; ++kt) {
    int cur = kt & 1, nxt = cur ^ 1;
    if (kt + 1 < kiters) {
      GLL(pAh, &ls[nxt][0][d0]); GLL(pAl, &ls[nxt][1][d0]);
      GLL(pBh, &ls[nxt][2][d0]); GLL(pBl, &ls[nxt][3][d0]);
      pAh += BK; pAl += BK; pBh += BK; pBl += BK;
    }
    short8 ah[2], al[2], bh[4], bl[4];
#pragma unroll
    for (int i = 0; i < 2; ++i) {
      int ra = (wm * 32 + i * 16 + c16) * BK + q * 8;
      ah[i] = *(const short8*)&ls[cur][0][ra];
      al[i] = *(const short8*)&ls[cur][1][ra];
    }
#pragma unroll
    for (int j = 0; j < 4; ++j) {
      int rb = (wn * 64 + j * 16 + c16) * BK + q * 8;
      bh[j] = *(const short8*)&ls[cur][2][rb];
      bl[j] = *(const short8*)&ls[cur][3][rb];
    }
#pragma unroll
    for (int mi = 0; mi < 2; ++mi)
#pragma unroll
      for (int ni = 0; ni < 4; ++ni) {
        acc[mi][ni] = __builtin_amdgcn_mfma_f32_16x16x32_bf16(ah[mi], bh[ni], acc[mi][ni], 0, 0, 0);
        acc[mi][ni] = __builtin_amdgcn_mfma_f32_16x16x32_bf16(ah[mi], bl[ni], acc[mi][ni], 0, 0, 0);
        acc[mi][ni] = __builtin_amdgcn_mfma_f32_16x16x32_bf16(al[mi], bh[ni], acc[mi][ni], 0, 0, 0);
      }
    __syncthreads();
  }

  float* Cz = C + (size_t)z * BSZ * ldc;
#pragma unroll
  for (int mi = 0; mi < 2; ++mi)
#pragma unroll
    for (int ni = 0; ni < 4; ++ni) {
      int n = n0 + wn * 64 + ni * 16 + c16;
      int mb = m0 + wm * 32 + mi * 16 + q * 4;
#pragma unroll
      for (int r = 0; r < 4; ++r)
        Cz[(size_t)(mb + r) * ldc + n] = acc[mi][ni][r];
    }
}

__global__ __launch_bounds__(256, 2) void gemm_cv(
    const ushort_t* __restrict__ Ahi, const ushort_t* __restrict__ Alo, int lda,
    const ushort_t* __restrict__ Bhi, const ushort_t* __restrict__ Blo, int ldbt,
    float* __restrict__ canvas, const float* __restrict__ x,
    const float* __restrict__ bdec,
    ushort_t* __restrict__ ehi, ushort_t* __restrict__ elo) {
  __shared__ ushort_t ls[2][4][TM * BK];
  int t = threadIdx.x;
  int m0 = blockIdx.y * TM, n0 = blockIdx.x * TN;
  int lane = t & 63, w = t >> 6;
  int wm = w >> 1, wn = w & 1;
  int q = lane >> 4, c16 = lane & 15;
  const int kiters = 8;

  const ushort_t* pAh = Ahi + (size_t)(m0 + (t >> 2)) * lda + (t & 3) * 8;
  const ushort_t* pAl = Alo + (size_t)(m0 + (t >> 2)) * lda + (t & 3) * 8;
  const ushort_t* pBh = Bhi + (size_t)(n0 + (t >> 2)) * ldbt + (t & 3) * 8;
  const ushort_t* pBl = Blo + (size_t)(n0 + (t >> 2)) * ldbt + (t & 3) * 8;
  const size_t a64 = (size_t)64 * lda, b64 = (size_t)64 * ldbt;
  const int d0 = t * 8;

  floatx4 acc[4][4];
#pragma unroll
  for (int i = 0; i < 4; ++i)
#pragma unroll
    for (int j = 0; j < 4; ++j) acc[i][j] = floatx4{0.f, 0.f, 0.f, 0.f};

  GLL(pAh, &ls[0][0][d0]); GLL(pAh + a64, &ls[0][0][d0 + 2048]);
  GLL(pAl, &ls[0][1][d0]); GLL(pAl + a64, &ls[0][1][d0 + 2048]);
  GLL(pBh, &ls[0][2][d0]); GLL(pBh + b64, &ls[0][2][d0 + 2048]);
  GLL(pBl, &ls[0][3][d0]); GLL(pBl + b64, &ls[0][3][d0 + 2048]);
  pAh += BK; pAl += BK; pBh += BK; pBl += BK;
  __syncthreads();

  for (int kt = 0; kt < kiters; ++kt) {
    int cur = kt & 1, nxt = cur ^ 1;
    if (kt + 1 < kiters) {
      GLL(pAh, &ls[nxt][0][d0]); GLL(pAh + a64, &ls[nxt][0][d0 + 2048]);
      GLL(pAl, &ls[nxt][1][d0]); GLL(pAl + a64, &ls[nxt][1][d0 + 2048]);
      GLL(pBh, &ls[nxt][2][d0]); GLL(pBh + b64, &ls[nxt][2][d0 + 2048]);
      GLL(pBl, &ls[nxt][3][d0]); GLL(pBl + b64, &ls[nxt][3][d0 + 2048]);
      pAh += BK; pAl += BK; pBh += BK; pBl += BK;
    }
    short8 ah[4], al[4], bh[4], bl[4];
#pragma unroll
    for (int i = 0; i < 4; ++i) {
      int ra = (wm * 64 + i * 16 + c16) * BK + q * 8;
      int rb = (wn * 64 + i * 16 + c16) * BK + q * 8;
      ah[i] = *(const short8*)&ls[cur][0][ra];
      al[i] = *(const short8*)&ls[cur][1][ra];
      bh[i] = *(const short8*)&ls[cur][2][rb];
      bl[i] = *(const short8*)&ls[cur][3][rb];
    }
#pragma unroll
    for (int mi = 0; mi < 4; ++mi)
#pragma unroll
      for (int ni = 0; ni < 4; ++ni) {
        acc[mi][ni] = __builtin_amdgcn_mfma_f32_16x16x32_bf16(ah[mi], bh[ni], acc[mi][ni], 0, 0, 0);
        acc[mi][ni] = __builtin_amdgcn_mfma_f32_16x16x32_bf16(ah[mi], bl[ni], acc[mi][ni], 0, 0, 0);
        acc[mi][ni] = __builtin_amdgcn_mfma_f32_16x16x32_bf16(al[mi], bh[ni], acc[mi][ni], 0, 0, 0);
      }
    __syncthreads();
  }

#pragma unroll
  for (int mi = 0; mi < 4; ++mi)
#pragma unroll
    for (int ni = 0; ni < 4; ++ni) {
      int n = n0 + wn * 64 + ni * 16 + c16;
      int mb = m0 + wm * 64 + mi * 16 + q * 4;
      float bv = bdec[n];
#pragma unroll
      for (int r = 0; r < 4; ++r) {
        int m = mb + r;
        size_t idx = (size_t)m * 4096 + n;
        float cv = canvas[idx] + acc[mi][ni][r] + bv;
        canvas[idx] = cv;
        float xh = x[idx] - sigm(cv);
        ushort_t h = f2b(xh);
        ehi[(size_t)m * KENC + n] = h;
        elo[(size_t)m * KENC + n] = f2b(xh - b2f(h));
      }
    }
}

__global__ __launch_bounds__(256) void k_enc(const float* __restrict__ zparts, int S,
                                             const float* __restrict__ ebias,
                                             float* __restrict__ c_enc,
                                             ushort_t* __restrict__ ehi,
                                             ushort_t* __restrict__ elo,
                                             const float* __restrict__ Wenc,
                                             const float* __restrict__ benc,
                                             ushort_t* __restrict__ dhi,
                                             ushort_t* __restrict__ dlo) {
  int b = blockIdx.x, u = threadIdx.x;
  float zi = ebias[u],       zf = ebias[u + 256];
  float zg = ebias[u + 512], zo = ebias[u + 768];
  for (int s = 0; s < S; ++s) {
    const float* z = zparts + ((size_t)s * BSZ + b) * GATES;
    zi += z[u]; zf += z[u + 256]; zg += z[u + 512]; zo += z[u + 768];
  }
  float c = c_enc[b * UNITS + u];
  float cn = sigm(zf) * c + sigm(zi) * tanhf(zg);
  float h = sigm(zo) * tanhf(cn);
  c_enc[b * UNITS + u] = cn;
  ushort_t hh = f2b(h);
  ehi[(size_t)b * KENC + 4352 + u] = hh;
  elo[(size_t)b * KENC + 4352 + u] = f2b(h - b2f(hh));

  __shared__ float sh[UNITS];
  __shared__ float slog[10];
  sh[u] = h;
  __syncthreads();
  if (u < 64) {
    float acc[10];
#pragma unroll
    for (int j = 0; j < 10; ++j) acc[j] = 0.f;
    for (int qq = 0; qq < 4; ++qq) {
      float hv = sh[u + qq * 64];
      const float* wr = Wenc + (u + qq * 64) * 10;
#pragma unroll
      for (int j = 0; j < 10; ++j) acc[j] += hv * wr[j];
    }
    for (int off = 32; off > 0; off >>= 1)
#pragma unroll
      for (int j = 0; j < 10; ++j) acc[j] += __shfl_down(acc[j], off);
    if (u == 0)
      for (int j = 0; j < 10; ++j) slog[j] = acc[j] + benc[j];
  }
  __syncthreads();
  float mx = slog[0];
  for (int j = 1; j < 10; ++j) mx = fmaxf(mx, slog[j]);
  float e[10], se = 0.f;
  for (int j = 0; j < 10; ++j) { e[j] = __expf(slog[j] - mx); se += e[j]; }
  float inv = 1.f / se;
  const float* wr = Wenc + u * 10;
  float zz = 0.f;
  for (int j = 0; j < 10; ++j) zz += e[j] * inv * wr[j];
  ushort_t zh = f2b(zz);
  dhi[(size_t)b * 512 + u] = zh;
  dlo[(size_t)b * 512 + u] = f2b(zz - b2f(zh));
}

__global__ __launch_bounds__(256) void k_dec(const float* __restrict__ zparts, int S,
                                             const float* __restrict__ dbias,
                                             float* __restrict__ c_dec,
                                             ushort_t* __restrict__ dhi,
                                             ushort_t* __restrict__ dlo,
                                             ushort_t* __restrict__ ehi,
                                             ushort_t* __restrict__ elo) {
  int b = blockIdx.x, u = threadIdx.x;
  float zi = dbias[u],       zf = dbias[u + 256];
  float zg = dbias[u + 512], zo = dbias[u + 768];
  for (int s = 0; s < S; ++s) {
    const float* z = zparts + ((size_t)s * BSZ + b) * GATES;
    zi += z[u]; zf += z[u + 256]; zg += z[u + 512]; zo += z[u + 768];
  }
  float c = c_dec[b * UNITS + u];
  float cn = sigm(zf) * c + sigm(zi) * tanhf(zg);
  float h = sigm(zo) * tanhf(cn);
  c_dec[b * UNITS + u] = cn;
  ushort_t hh = f2b(h);
  ushort_t hl = f2b(h - b2f(hh));
  dhi[(size_t)b * 512 + 256 + u] = hh;
  dlo[(size_t)b * 512 + 256 + u] = hl;
  ehi[(size_t)b * KENC + 4096 + u] = hh;
  elo[(size_t)b * KENC + 4096 + u] = hl;
}

// ===========================================================================
// COOPERATIVE MEGA-KERNEL: whole 10-step loop, grid 512 x 512thr, 2 blk/CU
// ===========================================================================
struct MegaArgs {
  const ushort_t *Wet_hi, *Wet_lo, *Wdt_hi, *Wdt_lo, *Wct_hi, *Wct_lo;
  ushort_t *ehi, *elo, *dhi, *dlo;
  float *zep, *zdp, *c_enc, *c_dec, *canvas;
  const float *x, *ebias, *dbias, *Wenc, *benc, *bdec;
};

// 64m x 128n tile GEMM phase; p -> xb(n-tile 0..7), mt(m-tile 0..7), zb(0..7)
// LDS buf layout (ushorts): Ah@0(2048) Al@2048 Bh@4096(4096) Bl@8192 ; stride 12288
__device__ __forceinline__ void gemm_phase(
    const ushort_t* __restrict__ Ahi, const ushort_t* __restrict__ Alo, int lda,
    const ushort_t* __restrict__ Bhi, const ushort_t* __restrict__ Blo, int ldbt,
    float* __restrict__ C, int ldc, int kiters, int p, int t, ushort_t* ls) {
  int xb = p & 7, mt = (p >> 3) & 7, zb = p >> 6;
  int m0 = mt * 64, n0 = xb * 128;
  int kstart = zb * kiters * 32;
  int lane = t & 63, w = t >> 6;
  int wm = w >> 2, wn = w & 3;               // 2 x 4 wave grid -> 32x32/wave
  int q = lane >> 4, c16 = lane & 15;
  int ta = t & 255;
  const ushort_t* pA = ((t < 256) ? Ahi : Alo)
                       + (size_t)(m0 + (ta >> 2)) * lda + kstart + (ta & 3) * 8;
  const ushort_t* pBh = Bhi + (size_t)(n0 + (t >> 2)) * ldbt + kstart + (t & 3) * 8;
  const ushort_t* pBl = Blo + (size_t)(n0 + (t >> 2)) * ldbt + kstart + (t & 3) * 8;
  const int dA = ((t < 256) ? 0 : 2048) + ta * 8;
  const int dBh = 4096 + t * 8, dBl = 8192 + t * 8;

  floatx4 acc[2][2];
#pragma unroll
  for (int i = 0; i < 2; ++i)
#pragma unroll
    for (int j = 0; j < 2; ++j) acc[i][j] = floatx4{0.f, 0.f, 0.f, 0.f};

  GLL(pA, ls + dA); GLL(pBh, ls + dBh); GLL(pBl, ls + dBl);
  pA += 32; pBh += 32; pBl += 32;
  __syncthreads();

  for (int kt = 0; kt < kiters; ++kt) {
    ushort_t* cur = ls + (kt & 1) * 12288;
    ushort_t* nxt = ls + ((kt & 1) ^ 1) * 12288;
    if (kt + 1 < kiters) {
      GLL(pA, nxt + dA); GLL(pBh, nxt + dBh); GLL(pBl, nxt + dBl);
      pA += 32; pBh += 32; pBl += 32;
    }
    short8 ah[2], al[2], bh[2], bl[2];
#pragma unroll
    for (int i = 0; i < 2; ++i) {
      int ra = (wm * 32 + i * 16 + c16) * 32 + q * 8;
      ah[i] = *(const short8*)(cur + ra);
      al[i] = *(const short8*)(cur + 2048 + ra);
      int rb = (wn * 32 + i * 16 + c16) * 32 + q * 8;
      bh[i] = *(const short8*)(cur + 4096 + rb);
      bl[i] = *(const short8*)(cur + 8192 + rb);
    }
#pragma unroll
    for (int mi = 0; mi < 2; ++mi)
#pragma unroll
      for (int ni = 0; ni < 2; ++ni) {
        acc[mi][ni] = __builtin_amdgcn_mfma_f32_16x16x32_bf16(ah[mi], bh[ni], acc[mi][ni], 0, 0, 0);
        acc[mi][ni] = __builtin_amdgcn_mfma_f32_16x16x32_bf16(ah[mi], bl[ni], acc[mi][ni], 0, 0, 0);
        acc[mi][ni] = __builtin_amdgcn_mfma_f32_16x16x32_bf16(al[mi], bh[ni], acc[mi][ni], 0, 0, 0);
      }
    __syncthreads();
  }

  float* Cz = C + (size_t)zb * BSZ * ldc;
#pragma unroll
  for (int mi = 0; mi < 2; ++mi)
#pragma unroll
    for (int ni = 0; ni < 2; ++ni) {
      int n = n0 + wn * 32 + ni * 16 + c16;
      int mb = m0 + wm * 32 + mi * 16 + q * 4;
#pragma unroll
      for (int r = 0; r < 4; ++r)
        Cz[(size_t)(mb + r) * ldc + n] = acc[mi][ni][r];
    }
}

// 64m x 64n canvas GEMM + fused x_hat. p -> nt(0..63), mt(0..7)
// LDS buf: Ah@0 Al@2048 Bh@4096 Bl@6144 ; stride 8192
__device__ __forceinline__ void cv_phase(
    const ushort_t* __restrict__ Ahi, const ushort_t* __restrict__ Alo,
    const ushort_t* __restrict__ Bhi, const ushort_t* __restrict__ Blo,
    float* __restrict__ canvas, const float* __restrict__ x,
    const float* __restrict__ bdec,
    ushort_t* __restrict__ ehi, ushort_t* __restrict__ elo,
    int p, int t, ushort_t* ls) {
  int nt = p & 63, mt = p >> 6;
  int m0 = mt * 64, n0 = nt * 64;
  const int kiters = 8;                       // K=256
  int lane = t & 63, w = t >> 6;
  int wm = w >> 2, wn = w & 3;                // 2 x 4 -> wave = 32m x 16n
  int q = lane >> 4, c16 = lane & 15;
  int ta = t & 255;
  const ushort_t* pA = ((t < 256) ? Ahi : Alo) + (size_t)(m0 + (ta >> 2)) * 512 + (ta & 3) * 8;
  const ushort_t* pB = ((t < 256) ? Bhi : Blo) + (size_t)(n0 + (ta >> 2)) * 256 + (ta & 3) * 8;
  const int dA = ((t < 256) ? 0 : 2048) + ta * 8;
  const int dB = ((t < 256) ? 4096 : 6144) + ta * 8;

  floatx4 acc[2];
  acc[0] = floatx4{0.f, 0.f, 0.f, 0.f};
  acc[1] = floatx4{0.f, 0.f, 0.f, 0.f};

  GLL(pA, ls + dA); GLL(pB, ls + dB);
  pA += 32; pB += 32;
  __syncthreads();

  for (int kt = 0; kt < kiters; ++kt) {
    ushort_t* cur = ls + (kt & 1) * 8192;
    ushort_t* nxt = ls + ((kt & 1) ^ 1) * 8192;
    if (kt + 1 < kiters) {
      GLL(pA, nxt + dA); GLL(pB, nxt + dB);
      pA += 32; pB += 32;
    }
    short8 ah[2], al[2], bh, bl;
#pragma unroll
    for (int i = 0; i < 2; ++i) {
      int ra = (wm * 32 + i * 16 + c16) * 32 + q * 8;
      ah[i] = *(const short8*)(cur + ra);
      al[i] = *(const short8*)(cur + 2048 + ra);
    }
    int rb = (wn * 16 + c16) * 32 + q * 8;
    bh = *(const short8*)(cur + 4096 + rb);
    bl = *(const short8*)(cur + 6144 + rb);
#pragma unroll
    for (int mi = 0; mi < 2; ++mi) {
      acc[mi] = __builtin_amdgcn_mfma_f32_16x16x32_bf16(ah[mi], bh, acc[mi], 0, 0, 0);
      acc[mi] = __builtin_amdgcn_mfma_f32_16x16x32_bf16(ah[mi], bl, acc[mi], 0, 0, 0);
      acc[mi] = __builtin_amdgcn_mfma_f32_16x16x32_bf16(al[mi], bh, acc[mi], 0, 0, 0);
    }
    __syncthreads();
  }

  int n = n0 + wn * 16 + c16;
  float bv = bdec[n];
#pragma unroll
  for (int mi = 0; mi < 2; ++mi) {
    int mb = m0 + wm * 32 + mi * 16 + q * 4;
#pragma unroll
    for (int r = 0; r < 4; ++r) {
      int m = mb + r;
      size_t idx = (size_t)m * 4096 + n;
      float cv = canvas[idx] + acc[mi][r] + bv;
      canvas[idx] = cv;
      float xh = x[idx] - sigm(cv);
      ushort_t h = f2b(xh);
      ehi[(size_t)m * KENC + n] = h;
      elo[(size_t)m * KENC + n] = f2b(xh - b2f(h));
    }
  }
}

__device__ __forceinline__ void enc_phase(const MegaArgs& a, int p, int t, float* shf) {
  int b = p;
  if (t < 256) {
    int u = t;
    float zi = a.ebias[u],       zf = a.ebias[u + 256];
    float zg = a.ebias[u + 512], zo = a.ebias[u + 768];
#pragma unroll
    for (int s = 0; s < ESPLIT; ++s) {
      const float* z = a.zep + ((size_t)s * BSZ + b) * GATES;
      zi += z[u]; zf += z[u + 256]; zg += z[u + 512]; zo += z[u + 768];
    }
    float c = a.c_enc[b * UNITS + u];
    float cn = sigm(zf) * c + sigm(zi) * tanhf(zg);
    float h = sigm(zo) * tanhf(cn);
    a.c_enc[b * UNITS + u] = cn;
    ushort_t hh = f2b(h);
    a.ehi[(size_t)b * KENC + 4352 + u] = hh;
    a.elo[(size_t)b * KENC + 4352 + u] = f2b(h - b2f(hh));
    shf[u] = h;
  }
  __syncthreads();
  if (t < 64) {
    float acc[10];
#pragma unroll
    for (int j = 0; j < 10; ++j) acc[j] = 0.f;
    for (int qq = 0; qq < 4; ++qq) {
      float hv = shf[t + qq * 64];
      const float* wr = a.Wenc + (t + qq * 64) * 10;
#pragma unroll
      for (int j = 0; j < 10; ++j) acc[j] += hv * wr[j];
    }
    for (int off = 32; off > 0; off >>= 1)
#pragma unroll
      for (int j = 0; j < 10; ++j) acc[j] += __shfl_down(acc[j], off);
    if (t == 0)
      for (int j = 0; j < 10; ++j) shf[256 + j] = acc[j] + a.benc[j];
  }
  __syncthreads();
  if (t < 256) {
    int u = t;
    float mx = shf[256];
    for (int j = 1; j < 10; ++j) mx = fmaxf(mx, shf[256 + j]);
    float e[10], se = 0.f;
    for (int j = 0; j < 10; ++j) { e[j] = __expf(shf[256 + j] - mx); se += e[j]; }
    float inv = 1.f / se;
    const float* wr = a.Wenc + u * 10;
    float zz = 0.f;
    for (int j = 0; j < 10; ++j) zz += e[j] * inv * wr[j];
    ushort_t zh = f2b(zz);
    a.dhi[(size_t)b * 512 + u] = zh;
    a.dlo[(size_t)b * 512 + u] = f2b(zz - b2f(zh));
  }
}

__device__ __forceinline__ void dec_phase(const MegaArgs& a, int p, int t) {
  if (t >= 256) return;
  int b = p, u = t;
  float zi = a.dbias[u],       zf = a.dbias[u + 256];
  float zg = a.dbias[u + 512], zo = a.dbias[u + 768];
#pragma unroll
  for (int s = 0; s < DSPLIT; ++s) {
    const float* z = a.zdp + ((size_t)s * BSZ + b) * GATES;
    zi += z[u]; zf += z[u + 256]; zg += z[u + 512]; zo += z[u + 768];
  }
  float c = a.c_dec[b * UNITS + u];
  float cn = sigm(zf) * c + sigm(zi) * tanhf(zg);
  float h = sigm(zo) * tanhf(cn);
  a.c_dec[b * UNITS + u] = cn;
  ushort_t hh = f2b(h);
  ushort_t hl = f2b(h - b2f(hh));
  a.dhi[(size_t)b * 512 + 256 + u] = hh;
  a.dlo[(size_t)b * 512 + 256 + u] = hl;
  a.ehi[(size_t)b * KENC + 4096 + u] = hh;
  a.elo[(size_t)b * KENC + 4096 + u] = hl;
}

__global__ __launch_bounds__(512, 4) void mega(MegaArgs a) {
  __shared__ ushort_t ls[24576];              // 48 KiB
  cg::grid_group grid = cg::this_grid();
  int p = blockIdx.x, t = threadIdx.x;
  float* shf = (float*)ls;
  for (int s = 0; s < STEPS; ++s) {
    // z_enc = ext @ Wet^T  (M=512,K=4608,N=1024), split-K 8x18
    gemm_phase(a.ehi, a.elo, KENC, a.Wet_hi, a.Wet_lo, KENC, a.zep, GATES, 18, p, t, ls);
    __threadfence(); grid.sync();
    enc_phase(a, p, t, shf);
    __threadfence(); grid.sync();
    // z_dec = [z|h_dec] @ Wdt^T (M=512,K=512,N=1024), split-K 8x2
    gemm_phase(a.dhi, a.dlo, 512, a.Wdt_hi, a.Wdt_lo, 512, a.zdp, GATES, 2, p, t, ls);
    __threadfence(); grid.sync();
    dec_phase(a, p, t);
    __threadfence(); grid.sync();
    // canvas += h_dec @ Wct^T + b_dec ; fused x_hat -> ext
    cv_phase(a.dhi + 256, a.dlo + 256, a.Wct_hi, a.Wct_lo, a.canvas, a.x, a.bdec,
             a.ehi, a.elo, p, t, ls);
    __threadfence(); grid.sync();
  }
}

// ---------------------------------------------------------------------------
extern "C" void kernel_launch(void* const* d_in, const int* in_sizes, int n_in,
                              void* d_out, int out_size, void* d_ws, size_t ws_size,
                              hipStream_t stream) {
  const float* x     = (const float*)d_in[0];
  const float* ek    = (const float*)d_in[1];   // [9728,1024]
  const float* er    = (const float*)d_in[2];   // [256,1024]
  const float* ebias = (const float*)d_in[3];
  const float* dk    = (const float*)d_in[4];   // [256,1024]
  const float* dr    = (const float*)d_in[5];   // [256,1024]
  const float* dbias = (const float*)d_in[6];
  const float* Wenc  = (const float*)d_in[7];   // [256,10]
  const float* benc  = (const float*)d_in[8];
  const float* Wdec  = (const float*)d_in[9];   // [256,4096]
  const float* bdec  = (const float*)d_in[10];

  float* canvas = (float*)d_out;                // [512, 4096] — persistent canvas

  char* p = (char*)d_ws;
  float* c_enc  = (float*)p;        p += (size_t)BSZ * UNITS * 4;
  float* c_dec  = (float*)p;        p += (size_t)BSZ * UNITS * 4;
  float* zep    = (float*)p;        p += (size_t)ESPLIT * BSZ * GATES * 4;
  float* zdp    = (float*)p;        p += (size_t)DSPLIT * BSZ * GATES * 4;
  ushort_t* ehi = (ushort_t*)p;     p += (size_t)BSZ * KENC * 2;
  ushort_t* elo = (ushort_t*)p;     p += (size_t)BSZ * KENC * 2;
  ushort_t* dhi = (ushort_t*)p;     p += (size_t)BSZ * 512 * 2;
  ushort_t* dlo = (ushort_t*)p;     p += (size_t)BSZ * 512 * 2;
  ushort_t* Wet_hi = (ushort_t*)p;  p += (size_t)GATES * KENC * 2;
  ushort_t* Wet_lo = (ushort_t*)p;  p += (size_t)GATES * KENC * 2;
  ushort_t* Wdt_hi = (ushort_t*)p;  p += (size_t)GATES * 512 * 2;
  ushort_t* Wdt_lo = (ushort_t*)p;  p += (size_t)GATES * 512 * 2;
  ushort_t* Wct_hi = (ushort_t*)p;  p += (size_t)4096 * UNITS * 2;
  ushort_t* Wct_lo = (ushort_t*)p;  p += (size_t)4096 * UNITS * 2;

  hipMemsetAsync(canvas, 0, (size_t)BSZ * 4096 * 4, stream);
  hipMemsetAsync(c_enc,  0, (size_t)BSZ * UNITS * 4, stream);
  hipMemsetAsync(c_dec,  0, (size_t)BSZ * UNITS * 4, stream);

  // ---- weight prep (once per launch) ----
  k_prep_pix<<<dim3(64, 16), 256, 0, stream>>>(ek, Wet_hi, Wet_lo);
  k_prep_sum<<<dim3(4, 16), 256, 0, stream>>>(ek + (size_t)9216 * GATES,
                                              ek + (size_t)9472 * GATES,
                                              GATES, KENC, 4096, Wet_hi, Wet_lo);
  k_prep_sum<<<dim3(4, 16), 256, 0, stream>>>(er, nullptr, GATES, KENC, 4352,
                                              Wet_hi, Wet_lo);
  k_prep_sum<<<dim3(4, 16), 256, 0, stream>>>(dk, nullptr, GATES, 512, 0,
                                              Wdt_hi, Wdt_lo);
  k_prep_sum<<<dim3(4, 16), 256, 0, stream>>>(dr, nullptr, GATES, 512, 256,
                                              Wdt_hi, Wdt_lo);
  k_prep_sum<<<dim3(4, 64), 256, 0, stream>>>(Wdec, nullptr, 4096, 256, 0,
                                              Wct_hi, Wct_lo);

  k_init<<<BSZ, 256, 0, stream>>>(ehi, elo, dhi, dlo);
  k_xhat0<<<(BSZ * 4096) / 256, 256, 0, stream>>>(x, ehi, elo);

  // decide path once per call (deterministic)
  int coop = 0, maxB = 0;
  hipDeviceGetAttribute(&coop, hipDeviceAttributeCooperativeLaunch, 0);
  hipOccupancyMaxActiveBlocksPerMultiprocessor(&maxB, (const void*)mega, 512, 0);

  if (coop && maxB >= 2) {
    MegaArgs ma;
    ma.Wet_hi = Wet_hi; ma.Wet_lo = Wet_lo;
    ma.Wdt_hi = Wdt_hi; ma.Wdt_lo = Wdt_lo;
    ma.Wct_hi = Wct_hi; ma.Wct_lo = Wct_lo;
    ma.ehi = ehi; ma.elo = elo; ma.dhi = dhi; ma.dlo = dlo;
    ma.zep = zep; ma.zdp = zdp; ma.c_enc = c_enc; ma.c_dec = c_dec;
    ma.canvas = canvas; ma.x = x; ma.ebias = ebias; ma.dbias = dbias;
    ma.Wenc = Wenc; ma.benc = benc; ma.bdec = bdec;
    void* params[] = { &ma };
    hipLaunchCooperativeKernel((const void*)mega, dim3(512), dim3(512),
                               params, 0, stream);
  } else {
    for (int s = 0; s < STEPS; ++s) {
      gemm128<<<dim3(GATES / 128, BSZ / 128, ESPLIT), 512, 0, stream>>>(
          ehi, elo, KENC, Wet_hi, Wet_lo, KENC, zep, GATES, 18);
      k_enc<<<BSZ, 256, 0, stream>>>(zep, ESPLIT, ebias, c_enc, ehi, elo, Wenc, benc, dhi, dlo);
      gemm128<<<dim3(GATES / 128, BSZ / 128, DSPLIT), 512, 0, stream>>>(
          dhi, dlo, 512, Wdt_hi, Wdt_lo, 512, zdp, GATES, 2);
      k_dec<<<BSZ, 256, 0, stream>>>(zdp, DSPLIT, dbias, c_dec, dhi, dlo, ehi, elo);
      gemm_cv<<<dim3(4096 / 128, BSZ / 128), 256, 0, stream>>>(
          dhi + 256, dlo + 256, 512, Wct_hi, Wct_lo, 256, canvas, x, bdec, ehi, elo);
    }
  }
}

// Round 10
// 931.987 us; speedup vs baseline: 1.0276x; 1.0276x over previous
//
#include <hip/hip_runtime.h>

typedef unsigned short ushort_t;
typedef __attribute__((ext_vector_type(8))) short short8;
typedef __attribute__((ext_vector_type(4))) float floatx4;

#define BSZ   512
#define UNITS 256
#define IMG   64
#define STEPS 10
#define GATES 1024
// folded ext layout per batch row: [x_hat 4096 | h_dec 256 | h_enc 256]
#define KENC  4608
#define ESPLIT 8    // 144 kt = 8 chunks of 18 -> 256 blocks (512 thr, 8 waves)
#define DSPLIT 8    // 16 kt  = 8 chunks of 2  -> 256 blocks

__device__ inline float b2f(ushort_t u) {
  union { float f; unsigned int i; } v; v.i = ((unsigned int)u) << 16; return v.f;
}
__device__ inline ushort_t f2b(float f) {
  unsigned int u = __float_as_uint(f);
  u += 0x7fffu + ((u >> 16) & 1u);          // round-to-nearest-even
  return (ushort_t)(u >> 16);
}
__device__ inline float sigm(float x) { return 1.f / (1.f + __expf(-x)); }

#define GLL(g, l) __builtin_amdgcn_global_load_lds(                      \
    (const __attribute__((address_space(1))) void*)(g),                  \
    (__attribute__((address_space(3))) void*)(l), 16, 0, 0)

// ---------------------------------------------------------------------------
// Fold patch weights into per-pixel weights + transpose + hi/lo split.
// ---------------------------------------------------------------------------
__global__ __launch_bounds__(256) void k_prep_pix(const float* __restrict__ ek,
                                                  ushort_t* __restrict__ ohi,
                                                  ushort_t* __restrict__ olo) {
  __shared__ float T[64][68];
  int t = threadIdx.x;
  int pix0 = blockIdx.x * 64, n0 = blockIdx.y * 64;
  int r = t >> 2, seg = t & 3;
  int pix = pix0 + r;
  int ri = pix >> 6, ci = pix & 63;
  float4 acc4[4];
#pragma unroll
  for (int j = 0; j < 4; ++j) acc4[j] = float4{0.f, 0.f, 0.f, 0.f};
#pragma unroll
  for (int di = 0; di < 3; ++di) {
    int ii = ri - di;
    if (ii < 0 || (ii & 1)) continue;
    int oi = ii >> 1;  if (oi >= 32) continue;
#pragma unroll
    for (int dj = 0; dj < 3; ++dj) {
      int jj = ci - dj;
      if (jj < 0 || (jj & 1)) continue;
      int oj = jj >> 1;  if (oj >= 32) continue;
      const float* row = ek + (size_t)((oi * 32 + oj) * 9 + di * 3 + dj) * GATES
                         + n0 + seg * 16;
#pragma unroll
      for (int j = 0; j < 4; ++j) {
        float4 v = *(const float4*)(row + j * 4);
        acc4[j].x += v.x; acc4[j].y += v.y; acc4[j].z += v.z; acc4[j].w += v.w;
      }
    }
  }
#pragma unroll
  for (int j = 0; j < 4; ++j) *(float4*)&T[r][seg * 16 + j * 4] = acc4[j];
  __syncthreads();
  ushort_t thi[16], tlo[16];
#pragma unroll
  for (int j = 0; j < 16; ++j) {
    float v = T[seg * 16 + j][r];
    ushort_t h = f2b(v);
    thi[j] = h;
    tlo[j] = f2b(v - b2f(h));
  }
  size_t off = (size_t)(n0 + r) * KENC + pix0 + seg * 16;
  *(uint4*)(ohi + off)     = *(const uint4*)&thi[0];
  *(uint4*)(ohi + off + 8) = *(const uint4*)&thi[8];
  *(uint4*)(olo + off)     = *(const uint4*)&tlo[0];
  *(uint4*)(olo + off + 8) = *(const uint4*)&tlo[8];
}

// ---------------------------------------------------------------------------
// Generic transpose + optional-sum + hi/lo split.
// ---------------------------------------------------------------------------
__global__ __launch_bounds__(256) void k_prep_sum(const float* __restrict__ s0,
                                                  const float* __restrict__ s1,
                                                  int src_ld, int out_ld, int koff,
                                                  ushort_t* __restrict__ ohi,
                                                  ushort_t* __restrict__ olo) {
  __shared__ float T[64][68];
  int t = threadIdx.x;
  int k0 = blockIdx.x * 64, n0 = blockIdx.y * 64;
  int r = t >> 2, seg = t & 3;
  const float* src = s0 + (size_t)(k0 + r) * src_ld + n0 + seg * 16;
  const float* src2 = s1 ? (s1 + (size_t)(k0 + r) * src_ld + n0 + seg * 16) : nullptr;
#pragma unroll
  for (int j = 0; j < 4; ++j) {
    float4 v = *(const float4*)(src + j * 4);
    if (src2) {
      float4 w = *(const float4*)(src2 + j * 4);
      v.x += w.x; v.y += w.y; v.z += w.z; v.w += w.w;
    }
    *(float4*)&T[r][seg * 16 + j * 4] = v;
  }
  __syncthreads();
  ushort_t thi[16], tlo[16];
#pragma unroll
  for (int j = 0; j < 16; ++j) {
    float v = T[seg * 16 + j][r];
    ushort_t h = f2b(v);
    thi[j] = h;
    tlo[j] = f2b(v - b2f(h));
  }
  size_t off = (size_t)(n0 + r) * out_ld + koff + k0 + seg * 16;
  *(uint4*)(ohi + off)     = *(const uint4*)&thi[0];
  *(uint4*)(ohi + off + 8) = *(const uint4*)&thi[8];
  *(uint4*)(olo + off)     = *(const uint4*)&tlo[0];
  *(uint4*)(olo + off + 8) = *(const uint4*)&tlo[8];
}

// ---------------------------------------------------------------------------
// Step-0 x_hat (canvas==0): x_hat = x - 0.5 into ext pixel region
// ---------------------------------------------------------------------------
__global__ __launch_bounds__(256) void k_xhat0(const float* __restrict__ x,
                                               ushort_t* __restrict__ ehi,
                                               ushort_t* __restrict__ elo) {
  int tid = blockIdx.x * 256 + threadIdx.x;       // 512*4096
  int b = tid >> 12, pix = tid & 4095;
  float v = x[tid] - 0.5f;
  ushort_t h = f2b(v);
  ehi[(size_t)b * KENC + pix] = h;
  elo[(size_t)b * KENC + pix] = f2b(v - b2f(h));
}

// ---------------------------------------------------------------------------
// Zero the state slots: ext h_dec/h_enc slots + dhi/dlo. grid 512 x 256 thr.
// ---------------------------------------------------------------------------
__global__ __launch_bounds__(256) void k_init(ushort_t* __restrict__ ehi,
                                              ushort_t* __restrict__ elo,
                                              ushort_t* __restrict__ dhi,
                                              ushort_t* __restrict__ dlo) {
  int b = blockIdx.x, u = threadIdx.x;
  ehi[(size_t)b * KENC + 4096 + u] = 0; ehi[(size_t)b * KENC + 4352 + u] = 0;
  elo[(size_t)b * KENC + 4096 + u] = 0; elo[(size_t)b * KENC + 4352 + u] = 0;
  dhi[(size_t)b * 512 + u] = 0; dhi[(size_t)b * 512 + 256 + u] = 0;
  dlo[(size_t)b * 512 + u] = 0; dlo[(size_t)b * 512 + 256 + u] = 0;
}

// ---------------------------------------------------------------------------
// ENC GEMM, 2-product: C = (Ahi+Alo) * Bhi^T  (weight lo-part dropped;
// error budget analysis: adds ~1.2e-3 pre-gate, damped ~4x through gates,
// reaches canvas only via downstream 3-product GEMMs).
// 128x128 tile, 512 threads = 8 waves (2 waves/SIMD), wave = 32x64,
// 16 MFMA/kt/wave. 3 LDS buffers (Ah,Al,Bh) double-buffered = 48 KiB.
// Split-K partial stores: C_part[z] = acc.
// ---------------------------------------------------------------------------
#define TM 128
#define TN 128
#define BK 32

__global__ __launch_bounds__(512, 2) void gemm_e(
    const ushort_t* __restrict__ Ahi, const ushort_t* __restrict__ Alo, int lda,
    const ushort_t* __restrict__ Bhi, int ldbt,
    float* __restrict__ C, int ldc, int kiters) {
  __shared__ ushort_t ls[2][3][TM * BK];   // 48 KiB
  int t = threadIdx.x;
  int m0 = blockIdx.y * TM, n0 = blockIdx.x * TN;
  int z = blockIdx.z;
  int kstart = z * kiters * BK;
  int lane = t & 63, w = t >> 6;            // 8 waves
  int wm = w >> 1, wn = w & 1;              // 4 x 2 wave grid -> 32m x 64n
  int q = lane >> 4, c16 = lane & 15;

  const ushort_t* pAh = Ahi + (size_t)(m0 + (t >> 2)) * lda + kstart + (t & 3) * 8;
  const ushort_t* pAl = Alo + (size_t)(m0 + (t >> 2)) * lda + kstart + (t & 3) * 8;
  const ushort_t* pBh = Bhi + (size_t)(n0 + (t >> 2)) * ldbt + kstart + (t & 3) * 8;
  const int d0 = t * 8;                     // 16 B per lane

  floatx4 acc[2][4];
#pragma unroll
  for (int i = 0; i < 2; ++i)
#pragma unroll
    for (int j = 0; j < 4; ++j) acc[i][j] = floatx4{0.f, 0.f, 0.f, 0.f};

  GLL(pAh, &ls[0][0][d0]); GLL(pAl, &ls[0][1][d0]); GLL(pBh, &ls[0][2][d0]);
  pAh += BK; pAl += BK; pBh += BK;
  __syncthreads();

  for (int kt = 0; kt < kiters; ++kt) {
    int cur = kt & 1, nxt = cur ^ 1;
    if (kt + 1 < kiters) {                  // prefetch kt+1 during MFMAs
      GLL(pAh, &ls[nxt][0][d0]); GLL(pAl, &ls[nxt][1][d0]); GLL(pBh, &ls[nxt][2][d0]);
      pAh += BK; pAl += BK; pBh += BK;
    }
    short8 ah[2], al[2], bh[4];
#pragma unroll
    for (int i = 0; i < 2; ++i) {
      int ra = (wm * 32 + i * 16 + c16) * BK + q * 8;
      ah[i] = *(const short8*)&ls[cur][0][ra];
      al[i] = *(const short8*)&ls[cur][1][ra];
    }
#pragma unroll
    for (int j = 0; j < 4; ++j) {
      int rb = (wn * 64 + j * 16 + c16) * BK + q * 8;
      bh[j] = *(const short8*)&ls[cur][2][rb];
    }
#pragma unroll
    for (int mi = 0; mi < 2; ++mi)
#pragma unroll
      for (int ni = 0; ni < 4; ++ni) {
        acc[mi][ni] = __builtin_amdgcn_mfma_f32_16x16x32_bf16(ah[mi], bh[ni], acc[mi][ni], 0, 0, 0);
        acc[mi][ni] = __builtin_amdgcn_mfma_f32_16x16x32_bf16(al[mi], bh[ni], acc[mi][ni], 0, 0, 0);
      }
    __syncthreads();
  }

  float* Cz = C + (size_t)z * BSZ * ldc;
#pragma unroll
  for (int mi = 0; mi < 2; ++mi)
#pragma unroll
    for (int ni = 0; ni < 4; ++ni) {
      int n = n0 + wn * 64 + ni * 16 + c16;
      int mb = m0 + wm * 32 + mi * 16 + q * 4;
#pragma unroll
      for (int r = 0; r < 4; ++r)
        Cz[(size_t)(mb + r) * ldc + n] = acc[mi][ni][r];
    }
}

// ---------------------------------------------------------------------------
// DEC GEMM, full 3-product (R8 config): 512 thr, 8 waves, 4 LDS buffers.
// ---------------------------------------------------------------------------
__global__ __launch_bounds__(512, 2) void gemm128(
    const ushort_t* __restrict__ Ahi, const ushort_t* __restrict__ Alo, int lda,
    const ushort_t* __restrict__ Bhi, const ushort_t* __restrict__ Blo, int ldbt,
    float* __restrict__ C, int ldc, int kiters) {
  __shared__ ushort_t ls[2][4][TM * BK];
  int t = threadIdx.x;
  int m0 = blockIdx.y * TM, n0 = blockIdx.x * TN;
  int z = blockIdx.z;
  int kstart = z * kiters * BK;
  int lane = t & 63, w = t >> 6;
  int wm = w >> 1, wn = w & 1;
  int q = lane >> 4, c16 = lane & 15;

  const ushort_t* pAh = Ahi + (size_t)(m0 + (t >> 2)) * lda + kstart + (t & 3) * 8;
  const ushort_t* pAl = Alo + (size_t)(m0 + (t >> 2)) * lda + kstart + (t & 3) * 8;
  const ushort_t* pBh = Bhi + (size_t)(n0 + (t >> 2)) * ldbt + kstart + (t & 3) * 8;
  const ushort_t* pBl = Blo + (size_t)(n0 + (t >> 2)) * ldbt + kstart + (t & 3) * 8;
  const int d0 = t * 8;

  floatx4 acc[2][4];
#pragma unroll
  for (int i = 0; i < 2; ++i)
#pragma unroll
    for (int j = 0; j < 4; ++j) acc[i][j] = floatx4{0.f, 0.f, 0.f, 0.f};

  GLL(pAh, &ls[0][0][d0]); GLL(pAl, &ls[0][1][d0]);
  GLL(pBh, &ls[0][2][d0]); GLL(pBl, &ls[0][3][d0]);
  pAh += BK; pAl += BK; pBh += BK; pBl += BK;
  __syncthreads();

  for (int kt = 0; kt < kiters; ++kt) {
    int cur = kt & 1, nxt = cur ^ 1;
    if (kt + 1 < kiters) {
      GLL(pAh, &ls[nxt][0][d0]); GLL(pAl, &ls[nxt][1][d0]);
      GLL(pBh, &ls[nxt][2][d0]); GLL(pBl, &ls[nxt][3][d0]);
      pAh += BK; pAl += BK; pBh += BK; pBl += BK;
    }
    short8 ah[2], al[2], bh[4], bl[4];
#pragma unroll
    for (int i = 0; i < 2; ++i) {
      int ra = (wm * 32 + i * 16 + c16) * BK + q * 8;
      ah[i] = *(const short8*)&ls[cur][0][ra];
      al[i] = *(const short8*)&ls[cur][1][ra];
    }
#pragma unroll
    for (int j = 0; j < 4; ++j) {
      int rb = (wn * 64 + j * 16 + c16) * BK + q * 8;
      bh[j] = *(const short8*)&ls[cur][2][rb];
      bl[j] = *(const short8*)&ls[cur][3][rb];
    }
#pragma unroll
    for (int mi = 0; mi < 2; ++mi)
#pragma unroll
      for (int ni = 0; ni < 4; ++ni) {
        acc[mi][ni] = __builtin_amdgcn_mfma_f32_16x16x32_bf16(ah[mi], bh[ni], acc[mi][ni], 0, 0, 0);
        acc[mi][ni] = __builtin_amdgcn_mfma_f32_16x16x32_bf16(ah[mi], bl[ni], acc[mi][ni], 0, 0, 0);
        acc[mi][ni] = __builtin_amdgcn_mfma_f32_16x16x32_bf16(al[mi], bh[ni], acc[mi][ni], 0, 0, 0);
      }
    __syncthreads();
  }

  float* Cz = C + (size_t)z * BSZ * ldc;
#pragma unroll
  for (int mi = 0; mi < 2; ++mi)
#pragma unroll
    for (int ni = 0; ni < 4; ++ni) {
      int n = n0 + wn * 64 + ni * 16 + c16;
      int mb = m0 + wm * 32 + mi * 16 + q * 4;
#pragma unroll
      for (int r = 0; r < 4; ++r)
        Cz[(size_t)(mb + r) * ldc + n] = acc[mi][ni][r];
    }
}

// ---------------------------------------------------------------------------
// Canvas GEMM with fused x_hat epilogue (M=512,N=4096,K=256), 3-product.
// ---------------------------------------------------------------------------
__global__ __launch_bounds__(256, 2) void gemm_cv(
    const ushort_t* __restrict__ Ahi, const ushort_t* __restrict__ Alo, int lda,
    const ushort_t* __restrict__ Bhi, const ushort_t* __restrict__ Blo, int ldbt,
    float* __restrict__ canvas, const float* __restrict__ x,
    const float* __restrict__ bdec,
    ushort_t* __restrict__ ehi, ushort_t* __restrict__ elo) {
  __shared__ ushort_t ls[2][4][TM * BK];
  int t = threadIdx.x;
  int m0 = blockIdx.y * TM, n0 = blockIdx.x * TN;
  int lane = t & 63, w = t >> 6;
  int wm = w >> 1, wn = w & 1;
  int q = lane >> 4, c16 = lane & 15;
  const int kiters = 8;

  const ushort_t* pAh = Ahi + (size_t)(m0 + (t >> 2)) * lda + (t & 3) * 8;
  const ushort_t* pAl = Alo + (size_t)(m0 + (t >> 2)) * lda + (t & 3) * 8;
  const ushort_t* pBh = Bhi + (size_t)(n0 + (t >> 2)) * ldbt + (t & 3) * 8;
  const ushort_t* pBl = Blo + (size_t)(n0 + (t >> 2)) * ldbt + (t & 3) * 8;
  const size_t a64 = (size_t)64 * lda, b64 = (size_t)64 * ldbt;
  const int d0 = t * 8;

  floatx4 acc[4][4];
#pragma unroll
  for (int i = 0; i < 4; ++i)
#pragma unroll
    for (int j = 0; j < 4; ++j) acc[i][j] = floatx4{0.f, 0.f, 0.f, 0.f};

  GLL(pAh, &ls[0][0][d0]); GLL(pAh + a64, &ls[0][0][d0 + 2048]);
  GLL(pAl, &ls[0][1][d0]); GLL(pAl + a64, &ls[0][1][d0 + 2048]);
  GLL(pBh, &ls[0][2][d0]); GLL(pBh + b64, &ls[0][2][d0 + 2048]);
  GLL(pBl, &ls[0][3][d0]); GLL(pBl + b64, &ls[0][3][d0 + 2048]);
  pAh += BK; pAl += BK; pBh += BK; pBl += BK;
  __syncthreads();

  for (int kt = 0; kt < kiters; ++kt) {
    int cur = kt & 1, nxt = cur ^ 1;
    if (kt + 1 < kiters) {
      GLL(pAh, &ls[nxt][0][d0]); GLL(pAh + a64, &ls[nxt][0][d0 + 2048]);
      GLL(pAl, &ls[nxt][1][d0]); GLL(pAl + a64, &ls[nxt][1][d0 + 2048]);
      GLL(pBh, &ls[nxt][2][d0]); GLL(pBh + b64, &ls[nxt][2][d0 + 2048]);
      GLL(pBl, &ls[nxt][3][d0]); GLL(pBl + b64, &ls[nxt][3][d0 + 2048]);
      pAh += BK; pAl += BK; pBh += BK; pBl += BK;
    }
    short8 ah[4], al[4], bh[4], bl[4];
#pragma unroll
    for (int i = 0; i < 4; ++i) {
      int ra = (wm * 64 + i * 16 + c16) * BK + q * 8;
      int rb = (wn * 64 + i * 16 + c16) * BK + q * 8;
      ah[i] = *(const short8*)&ls[cur][0][ra];
      al[i] = *(const short8*)&ls[cur][1][ra];
      bh[i] = *(const short8*)&ls[cur][2][rb];
      bl[i] = *(const short8*)&ls[cur][3][rb];
    }
#pragma unroll
    for (int mi = 0; mi < 4; ++mi)
#pragma unroll
      for (int ni = 0; ni < 4; ++ni) {
        acc[mi][ni] = __builtin_amdgcn_mfma_f32_16x16x32_bf16(ah[mi], bh[ni], acc[mi][ni], 0, 0, 0);
        acc[mi][ni] = __builtin_amdgcn_mfma_f32_16x16x32_bf16(ah[mi], bl[ni], acc[mi][ni], 0, 0, 0);
        acc[mi][ni] = __builtin_amdgcn_mfma_f32_16x16x32_bf16(al[mi], bh[ni], acc[mi][ni], 0, 0, 0);
      }
    __syncthreads();
  }

#pragma unroll
  for (int mi = 0; mi < 4; ++mi)
#pragma unroll
    for (int ni = 0; ni < 4; ++ni) {
      int n = n0 + wn * 64 + ni * 16 + c16;
      int mb = m0 + wm * 64 + mi * 16 + q * 4;
      float bv = bdec[n];
#pragma unroll
      for (int r = 0; r < 4; ++r) {
        int m = mb + r;
        size_t idx = (size_t)m * 4096 + n;
        float cv = canvas[idx] + acc[mi][ni][r] + bv;
        canvas[idx] = cv;
        float xh = x[idx] - sigm(cv);
        ushort_t h = f2b(xh);
        ehi[(size_t)m * KENC + n] = h;
        elo[(size_t)m * KENC + n] = f2b(xh - b2f(h));
      }
    }
}

// ---------------------------------------------------------------------------
// Encoder LSTM elementwise + attention softmax + glimpse; block = batch row
// ---------------------------------------------------------------------------
__global__ __launch_bounds__(256) void k_enc(const float* __restrict__ zparts, int S,
                                             const float* __restrict__ ebias,
                                             float* __restrict__ c_enc,
                                             ushort_t* __restrict__ ehi,
                                             ushort_t* __restrict__ elo,
                                             const float* __restrict__ Wenc,
                                             const float* __restrict__ benc,
                                             ushort_t* __restrict__ dhi,
                                             ushort_t* __restrict__ dlo) {
  int b = blockIdx.x, u = threadIdx.x;
  float zi = ebias[u],       zf = ebias[u + 256];
  float zg = ebias[u + 512], zo = ebias[u + 768];
  for (int s = 0; s < S; ++s) {
    const float* z = zparts + ((size_t)s * BSZ + b) * GATES;
    zi += z[u]; zf += z[u + 256]; zg += z[u + 512]; zo += z[u + 768];
  }
  float c = c_enc[b * UNITS + u];
  float cn = sigm(zf) * c + sigm(zi) * tanhf(zg);
  float h = sigm(zo) * tanhf(cn);
  c_enc[b * UNITS + u] = cn;
  ushort_t hh = f2b(h);
  ehi[(size_t)b * KENC + 4352 + u] = hh;
  elo[(size_t)b * KENC + 4352 + u] = f2b(h - b2f(hh));

  __shared__ float sh[UNITS];
  __shared__ float slog[10];
  sh[u] = h;
  __syncthreads();
  if (u < 64) {
    float acc[10];
#pragma unroll
    for (int j = 0; j < 10; ++j) acc[j] = 0.f;
    for (int qq = 0; qq < 4; ++qq) {
      float hv = sh[u + qq * 64];
      const float* wr = Wenc + (u + qq * 64) * 10;
#pragma unroll
      for (int j = 0; j < 10; ++j) acc[j] += hv * wr[j];
    }
    for (int off = 32; off > 0; off >>= 1)
#pragma unroll
      for (int j = 0; j < 10; ++j) acc[j] += __shfl_down(acc[j], off);
    if (u == 0)
      for (int j = 0; j < 10; ++j) slog[j] = acc[j] + benc[j];
  }
  __syncthreads();
  float mx = slog[0];
  for (int j = 1; j < 10; ++j) mx = fmaxf(mx, slog[j]);
  float e[10], se = 0.f;
  for (int j = 0; j < 10; ++j) { e[j] = __expf(slog[j] - mx); se += e[j]; }
  float inv = 1.f / se;
  const float* wr = Wenc + u * 10;
  float zz = 0.f;
  for (int j = 0; j < 10; ++j) zz += e[j] * inv * wr[j];
  ushort_t zh = f2b(zz);
  dhi[(size_t)b * 512 + u] = zh;
  dlo[(size_t)b * 512 + u] = f2b(zz - b2f(zh));
}

// ---------------------------------------------------------------------------
// Decoder LSTM elementwise; writes h_dec (hi/lo) into dec_in and ext
// ---------------------------------------------------------------------------
__global__ __launch_bounds__(256) void k_dec(const float* __restrict__ zparts, int S,
                                             const float* __restrict__ dbias,
                                             float* __restrict__ c_dec,
                                             ushort_t* __restrict__ dhi,
                                             ushort_t* __restrict__ dlo,
                                             ushort_t* __restrict__ ehi,
                                             ushort_t* __restrict__ elo) {
  int b = blockIdx.x, u = threadIdx.x;
  float zi = dbias[u],       zf = dbias[u + 256];
  float zg = dbias[u + 512], zo = dbias[u + 768];
  for (int s = 0; s < S; ++s) {
    const float* z = zparts + ((size_t)s * BSZ + b) * GATES;
    zi += z[u]; zf += z[u + 256]; zg += z[u + 512]; zo += z[u + 768];
  }
  float c = c_dec[b * UNITS + u];
  float cn = sigm(zf) * c + sigm(zi) * tanhf(zg);
  float h = sigm(zo) * tanhf(cn);
  c_dec[b * UNITS + u] = cn;
  ushort_t hh = f2b(h);
  ushort_t hl = f2b(h - b2f(hh));
  dhi[(size_t)b * 512 + 256 + u] = hh;
  dlo[(size_t)b * 512 + 256 + u] = hl;
  ehi[(size_t)b * KENC + 4096 + u] = hh;
  elo[(size_t)b * KENC + 4096 + u] = hl;
}

// ---------------------------------------------------------------------------
extern "C" void kernel_launch(void* const* d_in, const int* in_sizes, int n_in,
                              void* d_out, int out_size, void* d_ws, size_t ws_size,
                              hipStream_t stream) {
  const float* x     = (const float*)d_in[0];
  const float* ek    = (const float*)d_in[1];   // [9728,1024]
  const float* er    = (const float*)d_in[2];   // [256,1024]
  const float* ebias = (const float*)d_in[3];
  const float* dk    = (const float*)d_in[4];   // [256,1024]
  const float* dr    = (const float*)d_in[5];   // [256,1024]
  const float* dbias = (const float*)d_in[6];
  const float* Wenc  = (const float*)d_in[7];   // [256,10]
  const float* benc  = (const float*)d_in[8];
  const float* Wdec  = (const float*)d_in[9];   // [256,4096]
  const float* bdec  = (const float*)d_in[10];

  float* canvas = (float*)d_out;                // [512, 4096] — persistent canvas

  char* p = (char*)d_ws;
  float* c_enc  = (float*)p;        p += (size_t)BSZ * UNITS * 4;
  float* c_dec  = (float*)p;        p += (size_t)BSZ * UNITS * 4;
  float* zep    = (float*)p;        p += (size_t)ESPLIT * BSZ * GATES * 4;
  float* zdp    = (float*)p;        p += (size_t)DSPLIT * BSZ * GATES * 4;
  ushort_t* ehi = (ushort_t*)p;     p += (size_t)BSZ * KENC * 2;
  ushort_t* elo = (ushort_t*)p;     p += (size_t)BSZ * KENC * 2;
  ushort_t* dhi = (ushort_t*)p;     p += (size_t)BSZ * 512 * 2;
  ushort_t* dlo = (ushort_t*)p;     p += (size_t)BSZ * 512 * 2;
  ushort_t* Wet_hi = (ushort_t*)p;  p += (size_t)GATES * KENC * 2;      // [1024][4608]
  ushort_t* Wet_lo = (ushort_t*)p;  p += (size_t)GATES * KENC * 2;
  ushort_t* Wdt_hi = (ushort_t*)p;  p += (size_t)GATES * 512 * 2;       // [1024][512]
  ushort_t* Wdt_lo = (ushort_t*)p;  p += (size_t)GATES * 512 * 2;
  ushort_t* Wct_hi = (ushort_t*)p;  p += (size_t)4096 * UNITS * 2;      // [4096][256]
  ushort_t* Wct_lo = (ushort_t*)p;  p += (size_t)4096 * UNITS * 2;

  hipMemsetAsync(canvas, 0, (size_t)BSZ * 4096 * 4, stream);
  hipMemsetAsync(c_enc,  0, (size_t)BSZ * UNITS * 4, stream);
  hipMemsetAsync(c_dec,  0, (size_t)BSZ * UNITS * 4, stream);

  // ---- weight prep (once per launch) ----
  k_prep_pix<<<dim3(64, 16), 256, 0, stream>>>(ek, Wet_hi, Wet_lo);
  k_prep_sum<<<dim3(4, 16), 256, 0, stream>>>(ek + (size_t)9216 * GATES,
                                              ek + (size_t)9472 * GATES,
                                              GATES, KENC, 4096, Wet_hi, Wet_lo);
  k_prep_sum<<<dim3(4, 16), 256, 0, stream>>>(er, nullptr, GATES, KENC, 4352,
                                              Wet_hi, Wet_lo);
  k_prep_sum<<<dim3(4, 16), 256, 0, stream>>>(dk, nullptr, GATES, 512, 0,
                                              Wdt_hi, Wdt_lo);
  k_prep_sum<<<dim3(4, 16), 256, 0, stream>>>(dr, nullptr, GATES, 512, 256,
                                              Wdt_hi, Wdt_lo);
  k_prep_sum<<<dim3(4, 64), 256, 0, stream>>>(Wdec, nullptr, 4096, 256, 0,
                                              Wct_hi, Wct_lo);

  // state-slot zeroing + step-0 x_hat (canvas = 0)
  k_init<<<BSZ, 256, 0, stream>>>(ehi, elo, dhi, dlo);
  k_xhat0<<<(BSZ * 4096) / 256, 256, 0, stream>>>(x, ehi, elo);

  for (int s = 0; s < STEPS; ++s) {
    // z_enc = ext @ Wet_hi^T (M=512,K=4608,N=1024), 2-product, split-K 8x18
    gemm_e<<<dim3(GATES / 128, BSZ / 128, ESPLIT), 512, 0, stream>>>(
        ehi, elo, KENC, Wet_hi, KENC, zep, GATES, 18);
    k_enc<<<BSZ, 256, 0, stream>>>(zep, ESPLIT, ebias, c_enc, ehi, elo, Wenc, benc, dhi, dlo);
    // z_dec = [z|h_dec] @ Wdt^T (M=512,K=512,N=1024), 3-product, split-K 8x2
    gemm128<<<dim3(GATES / 128, BSZ / 128, DSPLIT), 512, 0, stream>>>(
        dhi, dlo, 512, Wdt_hi, Wdt_lo, 512, zdp, GATES, 2);
    k_dec<<<BSZ, 256, 0, stream>>>(zdp, DSPLIT, dbias, c_dec, dhi, dlo, ehi, elo);
    // canvas += h_dec @ Wct^T + b_dec ; fused x_hat -> ext (M=512,N=4096,K=256)
    gemm_cv<<<dim3(4096 / 128, BSZ / 128), 256, 0, stream>>>(
        dhi + 256, dlo + 256, 512, Wct_hi, Wct_lo, 256, canvas, x, bdec, ehi, elo);
  }
}

// Round 11
// 681.021 us; speedup vs baseline: 1.4063x; 1.3685x over previous
//
#include <hip/hip_runtime.h>

typedef unsigned short ushort_t;
typedef __attribute__((ext_vector_type(8))) short short8;
typedef __attribute__((ext_vector_type(4))) float floatx4;

#define BSZ   512
#define UNITS 256
#define IMG   64
#define STEPS 10
#define GATES 1024
// folded ext layout per batch row: [x_hat 4096 | h_dec 256 | h_enc 256]
#define KENC  4608
#define ESPLIT 8    // enc: 144 kt = 8 chunks of 18 -> 256 blocks (512 thr)
#define DSPLIT 4    // dec: 16 kt = 4 chunks of 4, 128x64 tiles -> 256 blocks

__device__ inline float b2f(ushort_t u) {
  union { float f; unsigned int i; } v; v.i = ((unsigned int)u) << 16; return v.f;
}
__device__ inline ushort_t f2b(float f) {
  unsigned int u = __float_as_uint(f);
  u += 0x7fffu + ((u >> 16) & 1u);          // round-to-nearest-even
  return (ushort_t)(u >> 16);
}
__device__ inline float sigm(float x) { return 1.f / (1.f + __expf(-x)); }

#define GLL(g, l) __builtin_amdgcn_global_load_lds(                      \
    (const __attribute__((address_space(1))) void*)(g),                  \
    (__attribute__((address_space(3))) void*)(l), 16, 0, 0)

// ---------------------------------------------------------------------------
// Fold patch weights into per-pixel weights + transpose (hi only — enc GEMM
// is pure bf16 now).
// ---------------------------------------------------------------------------
__global__ __launch_bounds__(256) void k_prep_pix(const float* __restrict__ ek,
                                                  ushort_t* __restrict__ ohi) {
  __shared__ float T[64][68];
  int t = threadIdx.x;
  int pix0 = blockIdx.x * 64, n0 = blockIdx.y * 64;
  int r = t >> 2, seg = t & 3;
  int pix = pix0 + r;
  int ri = pix >> 6, ci = pix & 63;
  float4 acc4[4];
#pragma unroll
  for (int j = 0; j < 4; ++j) acc4[j] = float4{0.f, 0.f, 0.f, 0.f};
#pragma unroll
  for (int di = 0; di < 3; ++di) {
    int ii = ri - di;
    if (ii < 0 || (ii & 1)) continue;
    int oi = ii >> 1;  if (oi >= 32) continue;
#pragma unroll
    for (int dj = 0; dj < 3; ++dj) {
      int jj = ci - dj;
      if (jj < 0 || (jj & 1)) continue;
      int oj = jj >> 1;  if (oj >= 32) continue;
      const float* row = ek + (size_t)((oi * 32 + oj) * 9 + di * 3 + dj) * GATES
                         + n0 + seg * 16;
#pragma unroll
      for (int j = 0; j < 4; ++j) {
        float4 v = *(const float4*)(row + j * 4);
        acc4[j].x += v.x; acc4[j].y += v.y; acc4[j].z += v.z; acc4[j].w += v.w;
      }
    }
  }
#pragma unroll
  for (int j = 0; j < 4; ++j) *(float4*)&T[r][seg * 16 + j * 4] = acc4[j];
  __syncthreads();
  ushort_t thi[16];
#pragma unroll
  for (int j = 0; j < 16; ++j) thi[j] = f2b(T[seg * 16 + j][r]);
  size_t off = (size_t)(n0 + r) * KENC + pix0 + seg * 16;
  *(uint4*)(ohi + off)     = *(const uint4*)&thi[0];
  *(uint4*)(ohi + off + 8) = *(const uint4*)&thi[8];
}

// ---------------------------------------------------------------------------
// Multi-job transpose prep (one dispatch). blockIdx.z selects job:
//  0: ek[9216..9472)+ek[9472..9728) -> Wet_hi @4096 (hi only)
//  1: er -> Wet_hi @4352 (hi only)
//  2: dk -> Wdt hi/lo @0     3: dr -> Wdt hi/lo @256
//  4..7: Wdec slice (z-4) -> Wct hi/lo
// ---------------------------------------------------------------------------
__global__ __launch_bounds__(256) void k_prep_multi(
    const float* __restrict__ ek, const float* __restrict__ er,
    const float* __restrict__ dk, const float* __restrict__ dr,
    const float* __restrict__ Wdec,
    ushort_t* __restrict__ Wet_hi,
    ushort_t* __restrict__ Wdt_hi, ushort_t* __restrict__ Wdt_lo,
    ushort_t* __restrict__ Wct_hi, ushort_t* __restrict__ Wct_lo) {
  __shared__ float T[64][68];
  int t = threadIdx.x;
  int z = blockIdx.z;
  int k0 = blockIdx.x * 64, n0 = blockIdx.y * 64;
  int r = t >> 2, seg = t & 3;

  const float *s0, *s1 = nullptr;
  ushort_t *ohi, *olo = nullptr;
  int src_ld, out_ld, koff;
  if (z == 0) { s0 = ek + (size_t)9216 * GATES; s1 = ek + (size_t)9472 * GATES;
                src_ld = GATES; ohi = Wet_hi; out_ld = KENC; koff = 4096; }
  else if (z == 1) { s0 = er; src_ld = GATES; ohi = Wet_hi; out_ld = KENC; koff = 4352; }
  else if (z == 2) { s0 = dk; src_ld = GATES; ohi = Wdt_hi; olo = Wdt_lo; out_ld = 512; koff = 0; }
  else if (z == 3) { s0 = dr; src_ld = GATES; ohi = Wdt_hi; olo = Wdt_lo; out_ld = 512; koff = 256; }
  else { s0 = Wdec; src_ld = 4096; ohi = Wct_hi; olo = Wct_lo; out_ld = 256; koff = 0;
         n0 += (z - 4) * 1024; }

  const float* src = s0 + (size_t)(k0 + r) * src_ld + n0 + seg * 16;
  const float* src2 = s1 ? (s1 + (size_t)(k0 + r) * src_ld + n0 + seg * 16) : nullptr;
#pragma unroll
  for (int j = 0; j < 4; ++j) {
    float4 v = *(const float4*)(src + j * 4);
    if (src2) {
      float4 w = *(const float4*)(src2 + j * 4);
      v.x += w.x; v.y += w.y; v.z += w.z; v.w += w.w;
    }
    *(float4*)&T[r][seg * 16 + j * 4] = v;
  }
  __syncthreads();
  ushort_t thi[16], tlo[16];
#pragma unroll
  for (int j = 0; j < 16; ++j) {
    float v = T[seg * 16 + j][r];
    ushort_t h = f2b(v);
    thi[j] = h;
    tlo[j] = f2b(v - b2f(h));
  }
  size_t off = (size_t)(n0 + r) * out_ld + koff + k0 + seg * 16;
  *(uint4*)(ohi + off)     = *(const uint4*)&thi[0];
  *(uint4*)(ohi + off + 8) = *(const uint4*)&thi[8];
  if (olo) {
    *(uint4*)(olo + off)     = *(const uint4*)&tlo[0];
    *(uint4*)(olo + off + 8) = *(const uint4*)&tlo[8];
  }
}

// ---------------------------------------------------------------------------
// Init: zero canvas, c_enc, c_dec, ext state slots, dhi/dlo. grid 512x256.
// ---------------------------------------------------------------------------
__global__ __launch_bounds__(256) void k_init(float* __restrict__ canvas,
                                              float* __restrict__ c_enc,
                                              float* __restrict__ c_dec,
                                              ushort_t* __restrict__ ehi,
                                              ushort_t* __restrict__ dhi,
                                              ushort_t* __restrict__ dlo) {
  int b = blockIdx.x, u = threadIdx.x;
  int gid = b * 256 + u;                     // 0..131071
  float4* cv4 = (float4*)canvas;             // 524288 float4
#pragma unroll
  for (int j = 0; j < 4; ++j) cv4[gid + j * 131072] = float4{0.f, 0.f, 0.f, 0.f};
  c_enc[gid] = 0.f; c_dec[gid] = 0.f;
  ehi[(size_t)b * KENC + 4096 + u] = 0; ehi[(size_t)b * KENC + 4352 + u] = 0;
  dhi[(size_t)b * 512 + u] = 0; dhi[(size_t)b * 512 + 256 + u] = 0;
  dlo[(size_t)b * 512 + u] = 0; dlo[(size_t)b * 512 + 256 + u] = 0;
}

// ---------------------------------------------------------------------------
// Step-0 x_hat (canvas==0): x_hat = x - 0.5 into ext pixel region (hi only)
// ---------------------------------------------------------------------------
__global__ __launch_bounds__(256) void k_xhat0(const float* __restrict__ x,
                                               ushort_t* __restrict__ ehi) {
  int tid = blockIdx.x * 256 + threadIdx.x;       // 512*4096
  int b = tid >> 12, pix = tid & 4095;
  ehi[(size_t)b * KENC + pix] = f2b(x[tid] - 0.5f);
}

// ---------------------------------------------------------------------------
// ENC GEMM, pure bf16 (1-product): C = Ahi * Bhi^T.
// 128x128 tile, 512 threads = 8 waves (2 waves/SIMD), wave = 32x64,
// 8 MFMA/kt/wave. 2 LDS buffers double-buffered = 32 KiB.
// Split-K partial stores: C_part[z] = acc.
// ---------------------------------------------------------------------------
#define TM 128
#define TN 128
#define BK 32

__global__ __launch_bounds__(512, 2) void gemm_e1(
    const ushort_t* __restrict__ Ahi, int lda,
    const ushort_t* __restrict__ Bhi, int ldbt,
    float* __restrict__ C, int ldc, int kiters) {
  __shared__ ushort_t ls[2][2][TM * BK];   // 32 KiB
  int t = threadIdx.x;
  int m0 = blockIdx.y * TM, n0 = blockIdx.x * TN;
  int z = blockIdx.z;
  int kstart = z * kiters * BK;
  int lane = t & 63, w = t >> 6;
  int wm = w >> 1, wn = w & 1;              // 4 x 2 wave grid -> 32m x 64n
  int q = lane >> 4, c16 = lane & 15;

  const ushort_t* pAh = Ahi + (size_t)(m0 + (t >> 2)) * lda + kstart + (t & 3) * 8;
  const ushort_t* pBh = Bhi + (size_t)(n0 + (t >> 2)) * ldbt + kstart + (t & 3) * 8;
  const int d0 = t * 8;

  floatx4 acc[2][4];
#pragma unroll
  for (int i = 0; i < 2; ++i)
#pragma unroll
    for (int j = 0; j < 4; ++j) acc[i][j] = floatx4{0.f, 0.f, 0.f, 0.f};

  GLL(pAh, &ls[0][0][d0]); GLL(pBh, &ls[0][1][d0]);
  pAh += BK; pBh += BK;
  __syncthreads();

  for (int kt = 0; kt < kiters; ++kt) {
    int cur = kt & 1, nxt = cur ^ 1;
    if (kt + 1 < kiters) {
      GLL(pAh, &ls[nxt][0][d0]); GLL(pBh, &ls[nxt][1][d0]);
      pAh += BK; pBh += BK;
    }
    short8 ah[2], bh[4];
#pragma unroll
    for (int i = 0; i < 2; ++i) {
      int ra = (wm * 32 + i * 16 + c16) * BK + q * 8;
      ah[i] = *(const short8*)&ls[cur][0][ra];
    }
#pragma unroll
    for (int j = 0; j < 4; ++j) {
      int rb = (wn * 64 + j * 16 + c16) * BK + q * 8;
      bh[j] = *(const short8*)&ls[cur][1][rb];
    }
#pragma unroll
    for (int mi = 0; mi < 2; ++mi)
#pragma unroll
      for (int ni = 0; ni < 4; ++ni)
        acc[mi][ni] = __builtin_amdgcn_mfma_f32_16x16x32_bf16(ah[mi], bh[ni], acc[mi][ni], 0, 0, 0);
    __syncthreads();
  }

  float* Cz = C + (size_t)z * BSZ * ldc;
#pragma unroll
  for (int mi = 0; mi < 2; ++mi)
#pragma unroll
    for (int ni = 0; ni < 4; ++ni) {
      int n = n0 + wn * 64 + ni * 16 + c16;
      int mb = m0 + wm * 32 + mi * 16 + q * 4;
#pragma unroll
      for (int r = 0; r < 4; ++r)
        Cz[(size_t)(mb + r) * ldc + n] = acc[mi][ni][r];
    }
}

// ---------------------------------------------------------------------------
// DEC GEMM, 3-product, 128x64 tile, 512 thr, split-K 4 (kiters=4).
// LDS per buf: Ah 8K, Al 8K, Bh 4K, Bl 4K = 24 KB; x2 = 48 KB.
// ---------------------------------------------------------------------------
__global__ __launch_bounds__(512, 2) void gemm_d(
    const ushort_t* __restrict__ Ahi, const ushort_t* __restrict__ Alo, int lda,
    const ushort_t* __restrict__ Bhi, const ushort_t* __restrict__ Blo, int ldbt,
    float* __restrict__ C, int ldc, int kiters) {
  __shared__ ushort_t ls[2][12288];        // 48 KiB; Ah@0 Al@4096 Bh@8192 Bl@10240
  int t = threadIdx.x;
  int m0 = blockIdx.y * TM, n0 = blockIdx.x * 64;
  int z = blockIdx.z;
  int kstart = z * kiters * BK;
  int lane = t & 63, w = t >> 6;
  int wm = w >> 1, wn = w & 1;              // 4 x 2 -> wave 32m x 32n
  int q = lane >> 4, c16 = lane & 15;
  int ta = t & 255;

  const ushort_t* pAh = Ahi + (size_t)(m0 + (t >> 2)) * lda + kstart + (t & 3) * 8;
  const ushort_t* pAl = Alo + (size_t)(m0 + (t >> 2)) * lda + kstart + (t & 3) * 8;
  const ushort_t* pB = ((t < 256) ? Bhi : Blo)
                       + (size_t)(n0 + (ta >> 2)) * ldbt + kstart + (ta & 3) * 8;
  const int dAh = t * 8, dAl = 4096 + t * 8;
  const int dB = ((t < 256) ? 8192 : 10240) + ta * 8;

  floatx4 acc[2][2];
#pragma unroll
  for (int i = 0; i < 2; ++i)
#pragma unroll
    for (int j = 0; j < 2; ++j) acc[i][j] = floatx4{0.f, 0.f, 0.f, 0.f};

  GLL(pAh, &ls[0][dAh]); GLL(pAl, &ls[0][dAl]); GLL(pB, &ls[0][dB]);
  pAh += BK; pAl += BK; pB += BK;
  __syncthreads();

  for (int kt = 0; kt < kiters; ++kt) {
    int cur = kt & 1, nxt = cur ^ 1;
    if (kt + 1 < kiters) {
      GLL(pAh, &ls[nxt][dAh]); GLL(pAl, &ls[nxt][dAl]); GLL(pB, &ls[nxt][dB]);
      pAh += BK; pAl += BK; pB += BK;
    }
    short8 ah[2], al[2], bh[2], bl[2];
#pragma unroll
    for (int i = 0; i < 2; ++i) {
      int ra = (wm * 32 + i * 16 + c16) * BK + q * 8;
      ah[i] = *(const short8*)&ls[cur][ra];
      al[i] = *(const short8*)&ls[cur][4096 + ra];
      int rb = (wn * 32 + i * 16 + c16) * BK + q * 8;
      bh[i] = *(const short8*)&ls[cur][8192 + rb];
      bl[i] = *(const short8*)&ls[cur][10240 + rb];
    }
#pragma unroll
    for (int mi = 0; mi < 2; ++mi)
#pragma unroll
      for (int ni = 0; ni < 2; ++ni) {
        acc[mi][ni] = __builtin_amdgcn_mfma_f32_16x16x32_bf16(ah[mi], bh[ni], acc[mi][ni], 0, 0, 0);
        acc[mi][ni] = __builtin_amdgcn_mfma_f32_16x16x32_bf16(ah[mi], bl[ni], acc[mi][ni], 0, 0, 0);
        acc[mi][ni] = __builtin_amdgcn_mfma_f32_16x16x32_bf16(al[mi], bh[ni], acc[mi][ni], 0, 0, 0);
      }
    __syncthreads();
  }

  float* Cz = C + (size_t)z * BSZ * ldc;
#pragma unroll
  for (int mi = 0; mi < 2; ++mi)
#pragma unroll
    for (int ni = 0; ni < 2; ++ni) {
      int n = n0 + wn * 32 + ni * 16 + c16;
      int mb = m0 + wm * 32 + mi * 16 + q * 4;
#pragma unroll
      for (int r = 0; r < 4; ++r)
        Cz[(size_t)(mb + r) * ldc + n] = acc[mi][ni][r];
    }
}

// ---------------------------------------------------------------------------
// Canvas GEMM with fused x_hat epilogue (M=512,N=4096,K=256), 3-product.
// ---------------------------------------------------------------------------
__global__ __launch_bounds__(256, 2) void gemm_cv(
    const ushort_t* __restrict__ Ahi, const ushort_t* __restrict__ Alo, int lda,
    const ushort_t* __restrict__ Bhi, const ushort_t* __restrict__ Blo, int ldbt,
    float* __restrict__ canvas, const float* __restrict__ x,
    const float* __restrict__ bdec, ushort_t* __restrict__ ehi) {
  __shared__ ushort_t ls[2][4][TM * BK];
  int t = threadIdx.x;
  int m0 = blockIdx.y * TM, n0 = blockIdx.x * TN;
  int lane = t & 63, w = t >> 6;
  int wm = w >> 1, wn = w & 1;
  int q = lane >> 4, c16 = lane & 15;
  const int kiters = 8;

  const ushort_t* pAh = Ahi + (size_t)(m0 + (t >> 2)) * lda + (t & 3) * 8;
  const ushort_t* pAl = Alo + (size_t)(m0 + (t >> 2)) * lda + (t & 3) * 8;
  const ushort_t* pBh = Bhi + (size_t)(n0 + (t >> 2)) * ldbt + (t & 3) * 8;
  const ushort_t* pBl = Blo + (size_t)(n0 + (t >> 2)) * ldbt + (t & 3) * 8;
  const size_t a64 = (size_t)64 * lda, b64 = (size_t)64 * ldbt;
  const int d0 = t * 8;

  floatx4 acc[4][4];
#pragma unroll
  for (int i = 0; i < 4; ++i)
#pragma unroll
    for (int j = 0; j < 4; ++j) acc[i][j] = floatx4{0.f, 0.f, 0.f, 0.f};

  GLL(pAh, &ls[0][0][d0]); GLL(pAh + a64, &ls[0][0][d0 + 2048]);
  GLL(pAl, &ls[0][1][d0]); GLL(pAl + a64, &ls[0][1][d0 + 2048]);
  GLL(pBh, &ls[0][2][d0]); GLL(pBh + b64, &ls[0][2][d0 + 2048]);
  GLL(pBl, &ls[0][3][d0]); GLL(pBl + b64, &ls[0][3][d0 + 2048]);
  pAh += BK; pAl += BK; pBh += BK; pBl += BK;
  __syncthreads();

  for (int kt = 0; kt < kiters; ++kt) {
    int cur = kt & 1, nxt = cur ^ 1;
    if (kt + 1 < kiters) {
      GLL(pAh, &ls[nxt][0][d0]); GLL(pAh + a64, &ls[nxt][0][d0 + 2048]);
      GLL(pAl, &ls[nxt][1][d0]); GLL(pAl + a64, &ls[nxt][1][d0 + 2048]);
      GLL(pBh, &ls[nxt][2][d0]); GLL(pBh + b64, &ls[nxt][2][d0 + 2048]);
      GLL(pBl, &ls[nxt][3][d0]); GLL(pBl + b64, &ls[nxt][3][d0 + 2048]);
      pAh += BK; pAl += BK; pBh += BK; pBl += BK;
    }
    short8 ah[4], al[4], bh[4], bl[4];
#pragma unroll
    for (int i = 0; i < 4; ++i) {
      int ra = (wm * 64 + i * 16 + c16) * BK + q * 8;
      int rb = (wn * 64 + i * 16 + c16) * BK + q * 8;
      ah[i] = *(const short8*)&ls[cur][0][ra];
      al[i] = *(const short8*)&ls[cur][1][ra];
      bh[i] = *(const short8*)&ls[cur][2][rb];
      bl[i] = *(const short8*)&ls[cur][3][rb];
    }
#pragma unroll
    for (int mi = 0; mi < 4; ++mi)
#pragma unroll
      for (int ni = 0; ni < 4; ++ni) {
        acc[mi][ni] = __builtin_amdgcn_mfma_f32_16x16x32_bf16(ah[mi], bh[ni], acc[mi][ni], 0, 0, 0);
        acc[mi][ni] = __builtin_amdgcn_mfma_f32_16x16x32_bf16(ah[mi], bl[ni], acc[mi][ni], 0, 0, 0);
        acc[mi][ni] = __builtin_amdgcn_mfma_f32_16x16x32_bf16(al[mi], bh[ni], acc[mi][ni], 0, 0, 0);
      }
    __syncthreads();
  }

#pragma unroll
  for (int mi = 0; mi < 4; ++mi)
#pragma unroll
    for (int ni = 0; ni < 4; ++ni) {
      int n = n0 + wn * 64 + ni * 16 + c16;
      int mb = m0 + wm * 64 + mi * 16 + q * 4;
      float bv = bdec[n];
#pragma unroll
      for (int r = 0; r < 4; ++r) {
        int m = mb + r;
        size_t idx = (size_t)m * 4096 + n;
        float cv = canvas[idx] + acc[mi][ni][r] + bv;
        canvas[idx] = cv;
        float xh = x[idx] - sigm(cv);
        ehi[(size_t)m * KENC + n] = f2b(xh);
      }
    }
}

// ---------------------------------------------------------------------------
// Encoder LSTM elementwise + attention softmax + glimpse; block = batch row
// ---------------------------------------------------------------------------
__global__ __launch_bounds__(256) void k_enc(const float* __restrict__ zparts, int S,
                                             const float* __restrict__ ebias,
                                             float* __restrict__ c_enc,
                                             ushort_t* __restrict__ ehi,
                                             const float* __restrict__ Wenc,
                                             const float* __restrict__ benc,
                                             ushort_t* __restrict__ dhi,
                                             ushort_t* __restrict__ dlo) {
  int b = blockIdx.x, u = threadIdx.x;
  float zi = ebias[u],       zf = ebias[u + 256];
  float zg = ebias[u + 512], zo = ebias[u + 768];
  for (int s = 0; s < S; ++s) {
    const float* z = zparts + ((size_t)s * BSZ + b) * GATES;
    zi += z[u]; zf += z[u + 256]; zg += z[u + 512]; zo += z[u + 768];
  }
  float c = c_enc[b * UNITS + u];
  float cn = sigm(zf) * c + sigm(zi) * tanhf(zg);
  float h = sigm(zo) * tanhf(cn);
  c_enc[b * UNITS + u] = cn;
  ehi[(size_t)b * KENC + 4352 + u] = f2b(h);

  __shared__ float sh[UNITS];
  __shared__ float slog[10];
  sh[u] = h;
  __syncthreads();
  if (u < 64) {
    float acc[10];
#pragma unroll
    for (int j = 0; j < 10; ++j) acc[j] = 0.f;
    for (int qq = 0; qq < 4; ++qq) {
      float hv = sh[u + qq * 64];
      const float* wr = Wenc + (u + qq * 64) * 10;
#pragma unroll
      for (int j = 0; j < 10; ++j) acc[j] += hv * wr[j];
    }
    for (int off = 32; off > 0; off >>= 1)
#pragma unroll
      for (int j = 0; j < 10; ++j) acc[j] += __shfl_down(acc[j], off);
    if (u == 0)
      for (int j = 0; j < 10; ++j) slog[j] = acc[j] + benc[j];
  }
  __syncthreads();
  float mx = slog[0];
  for (int j = 1; j < 10; ++j) mx = fmaxf(mx, slog[j]);
  float e[10], se = 0.f;
  for (int j = 0; j < 10; ++j) { e[j] = __expf(slog[j] - mx); se += e[j]; }
  float inv = 1.f / se;
  const float* wr = Wenc + u * 10;
  float zz = 0.f;
  for (int j = 0; j < 10; ++j) zz += e[j] * inv * wr[j];
  ushort_t zh = f2b(zz);
  dhi[(size_t)b * 512 + u] = zh;
  dlo[(size_t)b * 512 + u] = f2b(zz - b2f(zh));
}

// ---------------------------------------------------------------------------
// Decoder LSTM elementwise; writes h_dec hi/lo to dec_in, hi to ext slot
// ---------------------------------------------------------------------------
__global__ __launch_bounds__(256) void k_dec(const float* __restrict__ zparts, int S,
                                             const float* __restrict__ dbias,
                                             float* __restrict__ c_dec,
                                             ushort_t* __restrict__ dhi,
                                             ushort_t* __restrict__ dlo,
                                             ushort_t* __restrict__ ehi) {
  int b = blockIdx.x, u = threadIdx.x;
  float zi = dbias[u],       zf = dbias[u + 256];
  float zg = dbias[u + 512], zo = dbias[u + 768];
  for (int s = 0; s < S; ++s) {
    const float* z = zparts + ((size_t)s * BSZ + b) * GATES;
    zi += z[u]; zf += z[u + 256]; zg += z[u + 512]; zo += z[u + 768];
  }
  float c = c_dec[b * UNITS + u];
  float cn = sigm(zf) * c + sigm(zi) * tanhf(zg);
  float h = sigm(zo) * tanhf(cn);
  c_dec[b * UNITS + u] = cn;
  ushort_t hh = f2b(h);
  dhi[(size_t)b * 512 + 256 + u] = hh;
  dlo[(size_t)b * 512 + 256 + u] = f2b(h - b2f(hh));
  ehi[(size_t)b * KENC + 4096 + u] = hh;
}

// ---------------------------------------------------------------------------
extern "C" void kernel_launch(void* const* d_in, const int* in_sizes, int n_in,
                              void* d_out, int out_size, void* d_ws, size_t ws_size,
                              hipStream_t stream) {
  const float* x     = (const float*)d_in[0];
  const float* ek    = (const float*)d_in[1];   // [9728,1024]
  const float* er    = (const float*)d_in[2];   // [256,1024]
  const float* ebias = (const float*)d_in[3];
  const float* dk    = (const float*)d_in[4];   // [256,1024]
  const float* dr    = (const float*)d_in[5];   // [256,1024]
  const float* dbias = (const float*)d_in[6];
  const float* Wenc  = (const float*)d_in[7];   // [256,10]
  const float* benc  = (const float*)d_in[8];
  const float* Wdec  = (const float*)d_in[9];   // [256,4096]
  const float* bdec  = (const float*)d_in[10];

  float* canvas = (float*)d_out;                // [512, 4096] — persistent canvas

  char* p = (char*)d_ws;
  float* c_enc  = (float*)p;        p += (size_t)BSZ * UNITS * 4;
  float* c_dec  = (float*)p;        p += (size_t)BSZ * UNITS * 4;
  float* zep    = (float*)p;        p += (size_t)ESPLIT * BSZ * GATES * 4;
  float* zdp    = (float*)p;        p += (size_t)DSPLIT * BSZ * GATES * 4;
  ushort_t* ehi = (ushort_t*)p;     p += (size_t)BSZ * KENC * 2;
  ushort_t* dhi = (ushort_t*)p;     p += (size_t)BSZ * 512 * 2;
  ushort_t* dlo = (ushort_t*)p;     p += (size_t)BSZ * 512 * 2;
  ushort_t* Wet_hi = (ushort_t*)p;  p += (size_t)GATES * KENC * 2;      // [1024][4608]
  ushort_t* Wdt_hi = (ushort_t*)p;  p += (size_t)GATES * 512 * 2;       // [1024][512]
  ushort_t* Wdt_lo = (ushort_t*)p;  p += (size_t)GATES * 512 * 2;
  ushort_t* Wct_hi = (ushort_t*)p;  p += (size_t)4096 * UNITS * 2;      // [4096][256]
  ushort_t* Wct_lo = (ushort_t*)p;  p += (size_t)4096 * UNITS * 2;

  // ---- weight prep + init (once per launch) ----
  k_prep_pix<<<dim3(64, 16), 256, 0, stream>>>(ek, Wet_hi);
  k_prep_multi<<<dim3(4, 16, 8), 256, 0, stream>>>(ek, er, dk, dr, Wdec,
                                                   Wet_hi, Wdt_hi, Wdt_lo,
                                                   Wct_hi, Wct_lo);
  k_init<<<BSZ, 256, 0, stream>>>(canvas, c_enc, c_dec, ehi, dhi, dlo);
  k_xhat0<<<(BSZ * 4096) / 256, 256, 0, stream>>>(x, ehi);

  for (int s = 0; s < STEPS; ++s) {
    // z_enc = ext @ Wet_hi^T (M=512,K=4608,N=1024), 1-product bf16, split-K 8x18
    gemm_e1<<<dim3(GATES / 128, BSZ / 128, ESPLIT), 512, 0, stream>>>(
        ehi, KENC, Wet_hi, KENC, zep, GATES, 18);
    k_enc<<<BSZ, 256, 0, stream>>>(zep, ESPLIT, ebias, c_enc, ehi, Wenc, benc, dhi, dlo);
    // z_dec = [z|h_dec] @ Wdt^T (M=512,K=512,N=1024), 3-product, 128x64, split-K 4
    gemm_d<<<dim3(GATES / 64, BSZ / 128, DSPLIT), 512, 0, stream>>>(
        dhi, dlo, 512, Wdt_hi, Wdt_lo, 512, zdp, GATES, 4);
    k_dec<<<BSZ, 256, 0, stream>>>(zdp, DSPLIT, dbias, c_dec, dhi, dlo, ehi);
    // canvas += h_dec @ Wct^T + b_dec ; fused x_hat -> ext (M=512,N=4096,K=256)
    gemm_cv<<<dim3(4096 / 128, BSZ / 128), 256, 0, stream>>>(
        dhi + 256, dlo + 256, 512, Wct_hi, Wct_lo, 256, canvas, x, bdec, ehi);
  }
}